// Round 12
// baseline (10091.289 us; speedup 1.0000x reference)
//
#include <hip/hip_runtime.h>
#include <hip/hip_fp16.h>
#include <cstddef>

#define Bb 64
#define Tt 512
#define INRAW 225
#define Hh 256
#define G4 1024
#define Ee 512
#define NCODE 128
#define NCLS 250

typedef _Float16 half8_t __attribute__((ext_vector_type(8)));
typedef float f32x4 __attribute__((ext_vector_type(4)));
typedef unsigned u32x4 __attribute__((ext_vector_type(4)));

__device__ __forceinline__ float sigf(float x) { return 1.0f / (1.0f + expf(-x)); }
__device__ __forceinline__ float fsig(float x) { return __builtin_amdgcn_rcpf(1.0f + __expf(-x)); }
__device__ __forceinline__ float ftanh(float x) {
  return 2.0f * __builtin_amdgcn_rcpf(1.0f + __expf(-2.0f * x)) - 1.0f;
}

// packed signed-int16 max (VOP3P); fp16 sentinel 0x7C00 is the int16 max among
// {finite |h|<=1 patterns} ∪ {0x7C00}, so a pk_max fold detects any sentinel.
__device__ __forceinline__ unsigned pkmax16(unsigned a, unsigned b) {
  unsigned r;
  asm("v_pk_max_i16 %0, %1, %2" : "=v"(r) : "v"(a), "v"(b));
  return r;
}

// ------- fill hex exchange buffers with fp16 +inf sentinel (coherent x4) ------
__global__ __launch_bounds__(256) void fill_inf4_k(u32x4* __restrict__ p, long n4) {
  long i = (long)blockIdx.x * 256 + threadIdx.x;
  const long stride = (long)gridDim.x * 256;
  u32x4 v = {0x7C007C00u, 0x7C007C00u, 0x7C007C00u, 0x7C007C00u};
  for (; i < n4; i += stride) {
    asm volatile("global_store_dwordx4 %0, %1, off sc0 sc1" :: "v"(p + i), "v"(v) : "memory");
  }
}

// ---------------- x fp32 [32768][225] -> fp16 [32768][256] zero-padded --------
__global__ __launch_bounds__(256) void conv_x_h(const float* __restrict__ src,
                                                _Float16* __restrict__ dst) {
  int idx = blockIdx.x * 256 + threadIdx.x;   // 8,388,608 total
  int row = idx >> 8, k = idx & 255;
  dst[idx] = (k < INRAW) ? (_Float16)src[(size_t)row * INRAW + k] : (_Float16)0.f;
}

// ------- pack W[1024,K] -> wp[k][j(0..255)][g(0..3)] fp32 (dec_bwd only) ------
__global__ __launch_bounds__(256) void pack_w_k(const float* __restrict__ W,
                                                float* __restrict__ wp, int K) {
  int idx = blockIdx.x * 256 + threadIdx.x;   // = jg*K + k
  int jg = idx / K;
  if (jg >= 1024) return;
  int k = idx - jg * K;
  int j = jg >> 2, g = jg & 3;
  wp[(((size_t)k << 8) + j) * 4 + g] = W[(size_t)(g * 256 + j) * K + k];
}

// ------- pack Whh[1024,256] fp32 -> fp16 MFMA B-fragment stream (scan) --------
__global__ __launch_bounds__(256) void pack_w_frag(const float* __restrict__ W,
                                                   _Float16* __restrict__ wp) {
  int idx = blockIdx.x * 256 + threadIdx.x;   // 262144 total
  int e = idx & 7, l = (idx >> 3) & 63, zg = (idx >> 9) & 7;
  int ks = (idx >> 12) & 7, wv = (idx >> 15) & 7;
  int z = zg >> 2, g = zg & 3;
  int u = wv * 32 + z * 16 + (l & 15);
  int k = ks * 32 + (l >> 4) * 8 + e;
  wp[idx] = (_Float16)W[(size_t)(g * 256 + u) * 256 + k];
}

// ------- pack Wih[1024,Kraw] -> fp16 B-frag stream for gemm_mfma_pre ----------
// flat = ((((g*8+w)*2+z)*KS + ks)*64 + l)*8 + e ; k = ks*32+(l>>4)*8+e (0-pad)
__global__ __launch_bounds__(256) void pack_wih_frag(const float* __restrict__ W,
                                                     _Float16* __restrict__ wp,
                                                     int Kraw, int ksbits) {
  int idx = blockIdx.x * 256 + threadIdx.x;
  int KS = 1 << ksbits;
  int e = idx & 7, l = (idx >> 3) & 63;
  int tail = idx >> 9;
  int ks = tail & (KS - 1); tail >>= ksbits;
  int z = tail & 1, w = (tail >> 1) & 7, g = tail >> 4;
  if (g >= 4) return;
  int k = ks * 32 + (l >> 4) * 8 + e;
  int u = w * 32 + z * 16 + (l & 15);
  wp[idx] = (k < Kraw) ? (_Float16)W[(size_t)(g * 256 + u) * Kraw + k] : (_Float16)0.f;
}

// ---- MFMA input-projection GEMM: pre = A @ Wih^T + bias, fragment-layout out.
// grid (t=512, g=4); block 256 = 4 waves (batch-group). K = 256 or 512.
__global__ __launch_bounds__(256) void gemm_mfma_pre(const _Float16* __restrict__ Ah,
                                                     const _Float16* __restrict__ Bp,
                                                     const float* __restrict__ bias,
                                                     __half* __restrict__ C, int K) {
  const int t = blockIdx.x, g = blockIdx.y;
  const int bg = threadIdx.x >> 6;
  const int l = threadIdx.x & 63, l15 = l & 15, lg = l >> 4;
  const int KS = K >> 5;

  f32x4 acc[16];
#pragma unroll
  for (int ct = 0; ct < 16; ++ct) acc[ct] = (f32x4){0.f, 0.f, 0.f, 0.f};

  const _Float16* arow = Ah + ((size_t)(bg * 16 + l15) * 512 + t) * K + lg * 8;

  for (int kh = 0; kh < KS; kh += 8) {
    half8_t af[8];
#pragma unroll
    for (int k2 = 0; k2 < 8; ++k2)
      af[k2] = *(const half8_t*)(arow + (kh + k2) * 32);
#pragma unroll
    for (int ct = 0; ct < 16; ++ct) {
      const int w = ct >> 1, z = ct & 1;
      const _Float16* bb = Bp + ((((size_t)(g * 8 + w) * 2 + z) * KS + kh) * 64 + l) * 8;
#pragma unroll
      for (int k2 = 0; k2 < 8; ++k2) {
        half8_t bf = *(const half8_t*)(bb + (size_t)k2 * 512);
        acc[ct] = __builtin_amdgcn_mfma_f32_16x16x32_f16(af[k2], bf, acc[ct], 0, 0, 0);
      }
    }
  }

#pragma unroll
  for (int ct = 0; ct < 16; ++ct) {
    const int w = ct >> 1, z = ct & 1;
    const int u = w * 32 + z * 16 + l15;
    const float bs = bias[g * 256 + u];
    union { unsigned short us[4]; uint2 u2; } pk;
#pragma unroll
    for (int j = 0; j < 4; ++j) {
      __half hv = __float2half(acc[ct][j] + bs);
      pk.us[j] = *(unsigned short*)&hv;
    }
    __half* dst = C + ((((size_t)t * 4 + bg) * 8 + w) * 2 + z) * 1024 + l * 16 + g * 4;
    *(uint2*)dst = pk.u2;
  }
}

// ------ pairwise LSTM scan: per dir 8 blocks x 512 thr (8 waves) -------------
// block (uh,rh): units [uh*128,+128), rows [rh*16,+16). Wave wv = slice
// sl=uh*8+wv (16 units). Weights VGPR-resident (128/wave). Own-half h in LDS
// (XOR-swizzled, barrier); partner half via hex + sentinel-poll (R10 protocol).
__global__ __launch_bounds__(512, 1) void lstm_scan_pair(
    const half8_t* __restrict__ preA, const half8_t* __restrict__ wA,
    _Float16* __restrict__ hexA,
    const half8_t* __restrict__ preB, const half8_t* __restrict__ wB,
    _Float16* __restrict__ hexB, int nA) {
  const int isB = (blockIdx.x >= nA) ? 1 : 0;
  const half8_t* pre = isB ? preB : preA;
  const half8_t* wfrag = isB ? wB : wA;
  _Float16* hex = isB ? hexB : hexA;
  const int bid = blockIdx.x - (isB ? nA : 0);
  const int uh = bid & 1, rh = bid >> 1;
  const int wv = threadIdx.x >> 6;
  const int l = threadIdx.x & 63, l15 = l & 15, lg = l >> 4;
  const int sl = uh * 8 + wv;
  const int w_ = sl >> 1, z_ = sl & 1;

  __shared__ __align__(16) char hsh[2][4096];   // [buf][row16][ownunit128] fp16 swz

  // resident weights: 32 x half8 = 128 VGPR
  half8_t bfr[8][4];
#pragma unroll
  for (int ks = 0; ks < 8; ++ks)
#pragma unroll
    for (int g = 0; g < 4; ++g)
      bfr[ks][g] = wfrag[(size_t)((w_ * 8 + ks) * 8 + z_ * 4 + g) * 64 + l];

  float c[4] = {0.f, 0.f, 0.f, 0.f};
  half8_t pc0, pc1;
  {
    const int t0 = isB ? (Tt - 1) : 0;
    const half8_t* pp = pre + ((size_t)(t0 * 4 + rh) * 16 + sl) * 128 + l * 2;
    pc0 = pp[0]; pc1 = pp[1];
  }

  int cur = 0;
  for (int s = 0; s < Tt; ++s) {
    f32x4 acc[4];
#pragma unroll
    for (int g = 0; g < 4; ++g)
#pragma unroll
      for (int j = 0; j < 4; ++j)
        acc[g][j] = (float)((g < 2 ? pc0 : pc1)[(g & 1) * 4 + j]);

    if (s + 1 < Tt) {
      const int tn = isB ? (Tt - 2 - s) : (s + 1);
      const half8_t* pp = pre + ((size_t)(tn * 4 + rh) * 16 + sl) * 128 + l * 2;
      pc0 = pp[0]; pc1 = pp[1];
    }

    if (s > 0) {
      const char* ab = (const char*)hex + ((size_t)(s - 1) * 64 + rh * 16) * 512;
      half8_t afrP[4];

#define ISSUEP()                                                              \
      do {                                                                    \
        _Pragma("unroll")                                                     \
        for (int kk = 0; kk < 4; ++kk) {                                      \
          const void* ap = (const void*)(ab + l15 * 512 +                     \
                                         ((1 - uh) * 4 + kk) * 64 + lg * 16); \
          asm volatile("global_load_dwordx4 %0, %1, off sc0 sc1"              \
                       : "=v"(afrP[kk]) : "v"(ap) : "memory");                \
        }                                                                     \
      } while (0)

      // 1. issue partner loads early (RTT overlaps own-half MFMA)
      ISSUEP();

      // 2. own-half MFMA from LDS (no network wait)
      const char* rb = hsh[cur];
#pragma unroll
      for (int kk = 0; kk < 4; ++kk) {
        const int byte = (l15 * 256 + kk * 64 + lg * 16) ^ ((l15 & 7) << 4);
        half8_t ao = *(const half8_t*)(rb + byte);
#pragma unroll
        for (int g = 0; g < 4; ++g)
          acc[g] = __builtin_amdgcn_mfma_f32_16x16x32_f16(ao, bfr[uh * 4 + kk][g],
                                                          acc[g], 0, 0, 0);
      }

      // 3. sentinel poll on partner fragments
      while (true) {
        asm volatile("s_waitcnt vmcnt(0)" ::: "memory");
        __builtin_amdgcn_sched_barrier(0);
        union HU { half8_t h; u32x4 u; } cu;
        cu.h = afrP[0];
        unsigned mm = pkmax16(pkmax16(cu.u[0], cu.u[1]), pkmax16(cu.u[2], cu.u[3]));
#pragma unroll
        for (int kk = 1; kk < 4; ++kk) {
          cu.h = afrP[kk];
          mm = pkmax16(mm, pkmax16(pkmax16(cu.u[0], cu.u[1]), pkmax16(cu.u[2], cu.u[3])));
        }
        int bad = ((mm & 0xFFFFu) == 0x7C00u) || ((mm >> 16) == 0x7C00u);
        if (__all(!bad)) break;
        ISSUEP();
      }
      __builtin_amdgcn_sched_barrier(0);

      // 4. partner-half MFMA
#pragma unroll
      for (int kk = 0; kk < 4; ++kk)
#pragma unroll
        for (int g = 0; g < 4; ++g)
          acc[g] = __builtin_amdgcn_mfma_f32_16x16x32_f16(
              afrP[kk], bfr[(1 - uh) * 4 + kk][g], acc[g], 0, 0, 0);
#undef ISSUEP
    }

    // gates -> c,h; write own LDS buffer + publish to hex (coherent)
    char* wb = hsh[cur ^ 1];
#pragma unroll
    for (int j = 0; j < 4; ++j) {
      float iv = fsig(acc[0][j]);
      float fv = fsig(acc[1][j]);
      float gv = ftanh(acc[2][j]);
      float ov = fsig(acc[3][j]);
      c[j] = fv * c[j] + iv * gv;
      float hv = ov * ftanh(c[j]);
      const int rloc = lg * 4 + j;
      const int wbyte = (rloc * 256 + (wv * 16 + l15) * 2) ^ ((rloc & 7) << 4);
      union { _Float16 f; unsigned short u; } cv;
      cv.f = (_Float16)hv;
      *(_Float16*)(wb + wbyte) = cv.f;
      unsigned hb32 = cv.u;
      const void* hp = (const void*)(hex + ((size_t)s * 64 + rh * 16 + rloc) * 256
                                     + uh * 128 + wv * 16 + l15);
      asm volatile("global_store_short %0, %1, off sc0 sc1"
                   :: "v"(hp), "v"(hb32) : "memory");
    }
    __syncthreads();
    cur ^= 1;
  }
}

// ---------------- VQ: 4 vectors/block, 128 threads; writes qh fp16 ------------
#define VPB 4
__global__ __launch_bounds__(128) void vq_kernel(const _Float16* __restrict__ hexF,
                                                 const _Float16* __restrict__ hexB,
                                                 const float* __restrict__ cb,
                                                 _Float16* __restrict__ qh,
                                                 float* __restrict__ dmin) {
  const int tid = threadIdx.x;
  const int v0 = blockIdx.x * VPB;
  __shared__ __align__(16) float zs[VPB][Ee];
  __shared__ float dsh[NCODE];
  __shared__ int ish[NCODE];
  __shared__ int best[VPB];

#pragma unroll
  for (int v = 0; v < VPB; ++v) {
    const int vv = v0 + v;
    const int b = vv >> 9, t = vv & 511;
    const _Float16* hf = hexF + ((size_t)t * 64 + b) * 256;
    const _Float16* hb = hexB + ((size_t)(Tt - 1 - t) * 64 + b) * 256;
    zs[v][tid]       = (float)hf[tid];
    zs[v][tid + 128] = (float)hf[tid + 128];
    zs[v][tid + 256] = (float)hb[tid];
    zs[v][tid + 384] = (float)hb[tid + 128];
  }
  __syncthreads();

  float dv[VPB] = {0.0f, 0.0f, 0.0f, 0.0f};
  const float4* crow = (const float4*)(cb + (size_t)tid * Ee);
#pragma unroll 2
  for (int e4 = 0; e4 < Ee / 4; ++e4) {
    float4 cc = crow[e4];
#pragma unroll
    for (int v = 0; v < VPB; ++v) {
      float4 z = *(const float4*)&zs[v][e4 * 4];
      float t0 = z.x - cc.x, t1 = z.y - cc.y, t2 = z.z - cc.z, t3 = z.w - cc.w;
      dv[v] = fmaf(t0, t0, dv[v]);
      dv[v] = fmaf(t1, t1, dv[v]);
      dv[v] = fmaf(t2, t2, dv[v]);
      dv[v] = fmaf(t3, t3, dv[v]);
    }
  }

#pragma unroll
  for (int v = 0; v < VPB; ++v) {
    __syncthreads();
    dsh[tid] = dv[v];
    ish[tid] = tid;
    __syncthreads();
    for (int off = 64; off > 0; off >>= 1) {
      if (tid < off) {
        float dn = dsh[tid + off];
        int in_ = ish[tid + off];
        if (dn < dsh[tid] || (dn == dsh[tid] && in_ < ish[tid])) {
          dsh[tid] = dn;
          ish[tid] = in_;
        }
      }
      __syncthreads();
    }
    if (tid == 0) {
      best[v] = ish[0];
      dmin[v0 + v] = dsh[0];
    }
  }
  __syncthreads();

#pragma unroll
  for (int v = 0; v < VPB; ++v) {
    const float* cbest = cb + (size_t)best[v] * Ee;
    _Float16* qrow = qh + (size_t)(v0 + v) * Ee;
#pragma unroll
    for (int u = 0; u < 4; ++u) {
      int e = tid + u * 128;
      float z = zs[v][e];
      qrow[e] = (_Float16)(z + (cbest[e] - z));
    }
  }
}

// ---------------- vq loss reduce ----------------
__global__ __launch_bounds__(256) void vq_reduce(const float* __restrict__ dmin,
                                                 float* __restrict__ out) {
  __shared__ float sh[256];
  int tid = threadIdx.x;
  float s = 0.0f;
  for (int i = tid; i < Bb * Tt; i += 256) s += dmin[i];
  sh[tid] = s;
  __syncthreads();
  for (int off = 128; off > 0; off >>= 1) {
    if (tid < off) sh[tid] += sh[tid + off];
    __syncthreads();
  }
  if (tid == 0) out[Bb * NCLS] = sh[0] * (1.25f / ((float)(Bb * Tt) * (float)Ee));
}

// ---------------- decoder backward, single step at t=T-1 (h_prev=c_prev=0) ----
__global__ __launch_bounds__(256) void dec_bwd_last(const _Float16* __restrict__ qh,
                                                    const float* __restrict__ wpB,
                                                    const float* __restrict__ bias,
                                                    float* __restrict__ hb_last) {
  int b = blockIdx.x, tid = threadIdx.x;
  __shared__ __align__(16) float zsl[Ee];
  const _Float16* qrow = qh + ((size_t)b * Tt + (Tt - 1)) * Ee;
  zsl[tid] = (float)qrow[tid];
  zsl[tid + 256] = (float)qrow[tid + 256];
  __syncthreads();
  float a0 = bias[tid], a1 = bias[256 + tid], a2 = bias[512 + tid], a3 = bias[768 + tid];
  const float4* wp4 = (const float4*)wpB;
#pragma unroll 4
  for (int k = 0; k < Ee; ++k) {
    float zk = zsl[k];
    float4 w = wp4[((size_t)k << 8) + tid];
    a0 = fmaf(zk, w.x, a0); a1 = fmaf(zk, w.y, a1);
    a2 = fmaf(zk, w.z, a2); a3 = fmaf(zk, w.w, a3);
  }
  float i = sigf(a0), f = sigf(a1), g = tanhf(a2), o = sigf(a3);
  (void)f;
  float cc = i * g;
  hb_last[b * Hh + tid] = o * tanhf(cc);
}

// ---------------- classifier ----------------
__global__ __launch_bounds__(256) void classifier_k(const _Float16* __restrict__ hexD,
                                                    const float* __restrict__ hb_last,
                                                    const float* __restrict__ Wcls,
                                                    const float* __restrict__ bcls,
                                                    float* __restrict__ out) {
  int b = blockIdx.x, tid = threadIdx.x;
  __shared__ __align__(16) float dl[Ee];
  dl[tid] = (float)hexD[((size_t)(Tt - 1) * 64 + b) * 256 + tid];
  dl[tid + 256] = hb_last[b * Hh + tid];
  __syncthreads();
  if (tid < NCLS) {
    const float4* wr = (const float4*)(Wcls + (size_t)tid * Ee);
    float acc = bcls[tid];
#pragma unroll 4
    for (int e4 = 0; e4 < Ee / 4; ++e4) {
      float4 w = wr[e4];
      float4 z = *(const float4*)&dl[e4 * 4];
      acc = fmaf(w.x, z.x, acc);
      acc = fmaf(w.y, z.y, acc);
      acc = fmaf(w.z, z.z, acc);
      acc = fmaf(w.w, z.w, acc);
    }
    out[b * NCLS + tid] = acc;
  }
}

// ---------------- launch ----------------
extern "C" void kernel_launch(void* const* d_in, const int* in_sizes, int n_in,
                              void* d_out, int out_size, void* d_ws, size_t ws_size,
                              hipStream_t stream) {
  const float* x     = (const float*)d_in[0];
  const float* eWihF = (const float*)d_in[1];
  const float* eWhhF = (const float*)d_in[2];
  const float* ebF   = (const float*)d_in[3];
  const float* eWihB = (const float*)d_in[4];
  const float* eWhhB = (const float*)d_in[5];
  const float* ebB   = (const float*)d_in[6];
  const float* cb    = (const float*)d_in[7];
  const float* dWihF = (const float*)d_in[8];
  const float* dWhhF = (const float*)d_in[9];
  const float* dbF   = (const float*)d_in[10];
  const float* dWihB = (const float*)d_in[11];
  // d_in[12] = dec_Whh_b: unused (backward decoder state at t=T-1 starts from zero)
  const float* dbB   = (const float*)d_in[13];
  const float* Wcls  = (const float*)d_in[14];
  const float* bcls  = (const float*)d_in[15];
  float* out = (float*)d_out;
  float* w = (float*)d_ws;

  const size_t MR = (size_t)Bb * Tt;                 // 32768
  const size_t SZ_PRE_H = MR * G4 / 2;               // fp16 pre buffer, float units
  const size_t SZ_HEX  = (size_t)Tt * Bb * Hh / 2;   // fp16 exchange, float units
  const size_t SZ_XH   = MR * 256 / 2;               // xh fp16, float units
  const size_t SZ_WPK  = (size_t)512 * G4;           // dec_bwd fp32 pack
  const size_t SZ_WPH  = (size_t)G4 * Hh / 2;        // Whh frag pack, float units
  const size_t SZ_WIH  = (size_t)4 * 8 * 2 * 8 * 64 * 8 / 2;   // 131072 (enc, KS=8)
  const size_t SZ_WIHD = SZ_WIH * 2;                 // dec, KS=16

  size_t o = 0;
  __half* preFh = (__half*)(w + o); o += SZ_PRE_H;
  __half* preBh = (__half*)(w + o); o += SZ_PRE_H;
  _Float16* hexF = (_Float16*)(w + o); o += SZ_HEX;
  _Float16* hexB = (_Float16*)(w + o); o += SZ_HEX;
  _Float16* hexD = (_Float16*)(w + o); o += SZ_HEX;
  _Float16* xh = (_Float16*)(w + o); o += SZ_XH;
  float* wpkbd = w + o; o += SZ_WPK;
  _Float16* wphF = (_Float16*)(w + o); o += SZ_WPH;
  _Float16* wphB = (_Float16*)(w + o); o += SZ_WPH;
  _Float16* wphD = (_Float16*)(w + o); o += SZ_WPH;
  _Float16* wpihF = (_Float16*)(w + o); o += SZ_WIH;
  _Float16* wpihB = (_Float16*)(w + o); o += SZ_WIH;
  _Float16* wpihD = (_Float16*)(w + o); o += SZ_WIHD;
  float* dminp = w + o; o += MR;
  float* hbl   = w + o; o += (size_t)Bb * Hh;
  // aliases over dead regions
  _Float16* qh = (_Float16*)preFh;    // 32 MB fp16 over dead enc preF (post-scan)
  __half* dprf = preBh;               // dec fp16 pre over dead enc preB

  // 1. sentinel fill (hexF|hexB|hexD contiguous) + packs + x conversion
  hipLaunchKernelGGL(fill_inf4_k, dim3(2048), dim3(256), 0, stream,
                     (u32x4*)hexF, (long)(3 * SZ_HEX / 4));
  hipLaunchKernelGGL(conv_x_h, dim3((int)(MR * 256 / 256)), dim3(256), 0, stream, x, xh);
  hipLaunchKernelGGL(pack_w_k, dim3((G4 * 512) / 256), dim3(256), 0, stream, dWihB, wpkbd, 512);
  hipLaunchKernelGGL(pack_w_frag, dim3(1024), dim3(256), 0, stream, eWhhF, wphF);
  hipLaunchKernelGGL(pack_w_frag, dim3(1024), dim3(256), 0, stream, eWhhB, wphB);
  hipLaunchKernelGGL(pack_w_frag, dim3(1024), dim3(256), 0, stream, dWhhF, wphD);
  hipLaunchKernelGGL(pack_wih_frag, dim3(1024), dim3(256), 0, stream, eWihF, wpihF, INRAW, 3);
  hipLaunchKernelGGL(pack_wih_frag, dim3(1024), dim3(256), 0, stream, eWihB, wpihB, INRAW, 3);
  hipLaunchKernelGGL(pack_wih_frag, dim3(2048), dim3(256), 0, stream, dWihF, wpihD, Ee, 4);

  // 2. encoder input projections (MFMA)
  hipLaunchKernelGGL(gemm_mfma_pre, dim3(Tt, 4), dim3(256), 0, stream,
                     xh, wpihF, ebF, preFh, 256);
  hipLaunchKernelGGL(gemm_mfma_pre, dim3(Tt, 4), dim3(256), 0, stream,
                     xh, wpihB, ebB, preBh, 256);

  // 3. encoder scan: 16 pairwise blocks (8 fwd + 8 bwd), 512 threads each
  hipLaunchKernelGGL(lstm_scan_pair, dim3(16), dim3(512), 0, stream,
                     (const half8_t*)preFh, (const half8_t*)wphF, hexF,
                     (const half8_t*)preBh, (const half8_t*)wphB, hexB, 8);

  // 4. VQ + loss (writes qh fp16 over dead preF)
  hipLaunchKernelGGL(vq_kernel, dim3((int)(MR / VPB)), dim3(128), 0, stream,
                     hexF, hexB, cb, qh, dminp);
  hipLaunchKernelGGL(vq_reduce, dim3(1), dim3(256), 0, stream, dminp, out);

  // 5. decoder fwd input projection (MFMA, K=512)
  hipLaunchKernelGGL(gemm_mfma_pre, dim3(Tt, 4), dim3(256), 0, stream,
                     qh, wpihD, dbF, dprf, 512);

  // 6. decoder bwd (only t=T-1 contributes)
  hipLaunchKernelGGL(dec_bwd_last, dim3(Bb), dim3(256), 0, stream, qh, wpkbd, dbB, hbl);

  // 7. decoder fwd scan: 8 pairwise blocks
  hipLaunchKernelGGL(lstm_scan_pair, dim3(8), dim3(512), 0, stream,
                     (const half8_t*)dprf, (const half8_t*)wphD, hexD,
                     (const half8_t*)dprf, (const half8_t*)wphD, hexD, 8);

  // 8. classifier
  hipLaunchKernelGGL(classifier_k, dim3(Bb), dim3(256), 0, stream,
                     hexD, hbl, Wcls, bcls, out);
}

// Round 13
// 2877.881 us; speedup vs baseline: 3.5065x; 3.5065x over previous
//
#include <hip/hip_runtime.h>
#include <hip/hip_fp16.h>
#include <cstddef>

#define Bb 64
#define Tt 512
#define INRAW 225
#define Hh 256
#define G4 1024
#define Ee 512
#define NCODE 128
#define NCLS 250

typedef _Float16 half8_t __attribute__((ext_vector_type(8)));
typedef float f32x4 __attribute__((ext_vector_type(4)));
typedef unsigned u32x4 __attribute__((ext_vector_type(4)));

__device__ __forceinline__ float sigf(float x) { return 1.0f / (1.0f + expf(-x)); }
__device__ __forceinline__ float fsig(float x) { return __builtin_amdgcn_rcpf(1.0f + __expf(-x)); }
__device__ __forceinline__ float ftanh(float x) {
  return 2.0f * __builtin_amdgcn_rcpf(1.0f + __expf(-2.0f * x)) - 1.0f;
}

// packed signed-int16 max (VOP3P); fp16 sentinel 0x7C00 is the int16 max among
// {finite |h|<=1 patterns} ∪ {0x7C00}, so a pk_max fold detects any sentinel.
__device__ __forceinline__ unsigned pkmax16(unsigned a, unsigned b) {
  unsigned r;
  asm("v_pk_max_i16 %0, %1, %2" : "=v"(r) : "v"(a), "v"(b));
  return r;
}

// ------- fill hex exchange buffers with fp16 +inf sentinel (coherent x4) ------
__global__ __launch_bounds__(256) void fill_inf4_k(u32x4* __restrict__ p, long n4) {
  long i = (long)blockIdx.x * 256 + threadIdx.x;
  const long stride = (long)gridDim.x * 256;
  u32x4 v = {0x7C007C00u, 0x7C007C00u, 0x7C007C00u, 0x7C007C00u};
  for (; i < n4; i += stride) {
    asm volatile("global_store_dwordx4 %0, %1, off sc0 sc1" :: "v"(p + i), "v"(v) : "memory");
  }
}

// ---------------- x fp32 [32768][225] -> fp16 [32768][256] zero-padded --------
__global__ __launch_bounds__(256) void conv_x_h(const float* __restrict__ src,
                                                _Float16* __restrict__ dst) {
  int idx = blockIdx.x * 256 + threadIdx.x;   // 8,388,608 total
  int row = idx >> 8, k = idx & 255;
  dst[idx] = (k < INRAW) ? (_Float16)src[(size_t)row * INRAW + k] : (_Float16)0.f;
}

// ------- pack W[1024,K] -> wp[k][j(0..255)][g(0..3)] fp32 (dec_bwd only) ------
__global__ __launch_bounds__(256) void pack_w_k(const float* __restrict__ W,
                                                float* __restrict__ wp, int K) {
  int idx = blockIdx.x * 256 + threadIdx.x;   // = jg*K + k
  int jg = idx / K;
  if (jg >= 1024) return;
  int k = idx - jg * K;
  int j = jg >> 2, g = jg & 3;
  wp[(((size_t)k << 8) + j) * 4 + g] = W[(size_t)(g * 256 + j) * K + k];
}

// ------- pack Whh[1024,256] fp32 -> fp16 MFMA B-fragment stream (scan) --------
__global__ __launch_bounds__(256) void pack_w_frag(const float* __restrict__ W,
                                                   _Float16* __restrict__ wp) {
  int idx = blockIdx.x * 256 + threadIdx.x;   // 262144 total
  int e = idx & 7, l = (idx >> 3) & 63, zg = (idx >> 9) & 7;
  int ks = (idx >> 12) & 7, wv = (idx >> 15) & 7;
  int z = zg >> 2, g = zg & 3;
  int u = wv * 32 + z * 16 + (l & 15);
  int k = ks * 32 + (l >> 4) * 8 + e;
  wp[idx] = (_Float16)W[(size_t)(g * 256 + u) * 256 + k];
}

// ------- pack Wih[1024,Kraw] -> fp16 B-frag stream for gemm_mfma_pre ----------
// flat = ((((g*8+w)*2+z)*KS + ks)*64 + l)*8 + e ; k = ks*32+(l>>4)*8+e (0-pad)
__global__ __launch_bounds__(256) void pack_wih_frag(const float* __restrict__ W,
                                                     _Float16* __restrict__ wp,
                                                     int Kraw, int ksbits) {
  int idx = blockIdx.x * 256 + threadIdx.x;
  int KS = 1 << ksbits;
  int e = idx & 7, l = (idx >> 3) & 63;
  int tail = idx >> 9;
  int ks = tail & (KS - 1); tail >>= ksbits;
  int z = tail & 1, w = (tail >> 1) & 7, g = tail >> 4;
  if (g >= 4) return;
  int k = ks * 32 + (l >> 4) * 8 + e;
  int u = w * 32 + z * 16 + (l & 15);
  wp[idx] = (k < Kraw) ? (_Float16)W[(size_t)(g * 256 + u) * Kraw + k] : (_Float16)0.f;
}

// ---- MFMA input-projection GEMM: pre = A @ Wih^T + bias, fragment-layout out.
// grid (t=512, g=4); block 256 = 4 waves (batch-group). K = 256 or 512.
__global__ __launch_bounds__(256) void gemm_mfma_pre(const _Float16* __restrict__ Ah,
                                                     const _Float16* __restrict__ Bp,
                                                     const float* __restrict__ bias,
                                                     __half* __restrict__ C, int K) {
  const int t = blockIdx.x, g = blockIdx.y;
  const int bg = threadIdx.x >> 6;
  const int l = threadIdx.x & 63, l15 = l & 15, lg = l >> 4;
  const int KS = K >> 5;

  f32x4 acc[16];
#pragma unroll
  for (int ct = 0; ct < 16; ++ct) acc[ct] = (f32x4){0.f, 0.f, 0.f, 0.f};

  const _Float16* arow = Ah + ((size_t)(bg * 16 + l15) * 512 + t) * K + lg * 8;

  for (int kh = 0; kh < KS; kh += 8) {
    half8_t af[8];
#pragma unroll
    for (int k2 = 0; k2 < 8; ++k2)
      af[k2] = *(const half8_t*)(arow + (kh + k2) * 32);
#pragma unroll
    for (int ct = 0; ct < 16; ++ct) {
      const int w = ct >> 1, z = ct & 1;
      const _Float16* bb = Bp + ((((size_t)(g * 8 + w) * 2 + z) * KS + kh) * 64 + l) * 8;
#pragma unroll
      for (int k2 = 0; k2 < 8; ++k2) {
        half8_t bf = *(const half8_t*)(bb + (size_t)k2 * 512);
        acc[ct] = __builtin_amdgcn_mfma_f32_16x16x32_f16(af[k2], bf, acc[ct], 0, 0, 0);
      }
    }
  }

#pragma unroll
  for (int ct = 0; ct < 16; ++ct) {
    const int w = ct >> 1, z = ct & 1;
    const int u = w * 32 + z * 16 + l15;
    const float bs = bias[g * 256 + u];
    union { unsigned short us[4]; uint2 u2; } pk;
#pragma unroll
    for (int j = 0; j < 4; ++j) {
      __half hv = __float2half(acc[ct][j] + bs);
      pk.us[j] = *(unsigned short*)&hv;
    }
    __half* dst = C + ((((size_t)t * 4 + bg) * 8 + w) * 2 + z) * 1024 + l * 16 + g * 4;
    *(uint2*)dst = pk.u2;
  }
}

// ------ pairwise LSTM scan (STATIC weight indexing — rule #20 fix) -----------
// per dir 8 blocks x 512 thr; block (uh,rh): units [uh*128,+128), rows
// [rh*16,+16). bOwn/bPar statically indexed (uh only in load ADDRESSES).
__global__ __launch_bounds__(512, 1) void lstm_scan_pair(
    const half8_t* __restrict__ preA, const half8_t* __restrict__ wA,
    _Float16* __restrict__ hexA,
    const half8_t* __restrict__ preB, const half8_t* __restrict__ wB,
    _Float16* __restrict__ hexB, int nA) {
  const int isB = (blockIdx.x >= nA) ? 1 : 0;
  const half8_t* pre = isB ? preB : preA;
  const half8_t* wfrag = isB ? wB : wA;
  _Float16* hex = isB ? hexB : hexA;
  const int bid = blockIdx.x - (isB ? nA : 0);
  const int uh = bid & 1, rh = bid >> 1;
  const int wv = threadIdx.x >> 6;
  const int l = threadIdx.x & 63, l15 = l & 15, lg = l >> 4;
  const int sl = uh * 8 + wv;
  const int w_ = sl >> 1, z_ = sl & 1;

  __shared__ __align__(16) char hsh[2][4096];   // [buf][row16][ownunit128] fp16 swz

  // resident weights: static arrays, runtime uh only in addresses
  half8_t bOwn[4][4], bPar[4][4];
#pragma unroll
  for (int kk = 0; kk < 4; ++kk)
#pragma unroll
    for (int g = 0; g < 4; ++g) {
      bOwn[kk][g] = wfrag[(size_t)((w_ * 8 + uh * 4 + kk) * 8 + z_ * 4 + g) * 64 + l];
      bPar[kk][g] = wfrag[(size_t)((w_ * 8 + (1 - uh) * 4 + kk) * 8 + z_ * 4 + g) * 64 + l];
    }

  float c[4] = {0.f, 0.f, 0.f, 0.f};
  half8_t pc0, pc1;
  {
    const int t0 = isB ? (Tt - 1) : 0;
    const half8_t* pp = pre + ((size_t)(t0 * 4 + rh) * 16 + sl) * 128 + l * 2;
    pc0 = pp[0]; pc1 = pp[1];
  }

  int cur = 0;
  for (int s = 0; s < Tt; ++s) {
    f32x4 acc[4];
#pragma unroll
    for (int g = 0; g < 4; ++g)
#pragma unroll
      for (int j = 0; j < 4; ++j)
        acc[g][j] = (float)((g < 2 ? pc0 : pc1)[(g & 1) * 4 + j]);

    if (s + 1 < Tt) {
      const int tn = isB ? (Tt - 2 - s) : (s + 1);
      const half8_t* pp = pre + ((size_t)(tn * 4 + rh) * 16 + sl) * 128 + l * 2;
      pc0 = pp[0]; pc1 = pp[1];
    }

    if (s > 0) {
      // partner base: row-major hex, partner half at byte offset (1-uh)*256
      const char* ab = (const char*)hex + ((size_t)(s - 1) * 64 + rh * 16) * 512
                       + (1 - uh) * 256;
      half8_t afrP[4];

#define ISSUEP()                                                              \
      do {                                                                    \
        _Pragma("unroll")                                                     \
        for (int kk = 0; kk < 4; ++kk) {                                      \
          const void* ap = (const void*)(ab + l15 * 512 + kk * 64 + lg * 16); \
          asm volatile("global_load_dwordx4 %0, %1, off sc0 sc1"              \
                       : "=v"(afrP[kk]) : "v"(ap) : "memory");                \
        }                                                                     \
      } while (0)

      // 1. issue partner loads early (RTT overlaps own-half MFMA)
      ISSUEP();

      // 2. own-half MFMA from LDS (no network wait)
      const char* rb = hsh[cur];
#pragma unroll
      for (int kk = 0; kk < 4; ++kk) {
        const int byte = (l15 * 256 + kk * 64 + lg * 16) ^ ((l15 & 7) << 4);
        half8_t ao = *(const half8_t*)(rb + byte);
#pragma unroll
        for (int g = 0; g < 4; ++g)
          acc[g] = __builtin_amdgcn_mfma_f32_16x16x32_f16(ao, bOwn[kk][g],
                                                          acc[g], 0, 0, 0);
      }

      // 3. sentinel poll on partner fragments
      while (true) {
        asm volatile("s_waitcnt vmcnt(0)" ::: "memory");
        __builtin_amdgcn_sched_barrier(0);
        union HU { half8_t h; u32x4 u; } cu;
        cu.h = afrP[0];
        unsigned mm = pkmax16(pkmax16(cu.u[0], cu.u[1]), pkmax16(cu.u[2], cu.u[3]));
#pragma unroll
        for (int kk = 1; kk < 4; ++kk) {
          cu.h = afrP[kk];
          mm = pkmax16(mm, pkmax16(pkmax16(cu.u[0], cu.u[1]), pkmax16(cu.u[2], cu.u[3])));
        }
        int bad = ((mm & 0xFFFFu) == 0x7C00u) || ((mm >> 16) == 0x7C00u);
        if (__all(!bad)) break;
        ISSUEP();
      }
      __builtin_amdgcn_sched_barrier(0);

      // 4. partner-half MFMA (static indices)
#pragma unroll
      for (int kk = 0; kk < 4; ++kk)
#pragma unroll
        for (int g = 0; g < 4; ++g)
          acc[g] = __builtin_amdgcn_mfma_f32_16x16x32_f16(
              afrP[kk], bPar[kk][g], acc[g], 0, 0, 0);
#undef ISSUEP
    }

    // gates -> c,h; write own LDS buffer + publish to hex (coherent)
    char* wb = hsh[cur ^ 1];
#pragma unroll
    for (int j = 0; j < 4; ++j) {
      float iv = fsig(acc[0][j]);
      float fv = fsig(acc[1][j]);
      float gv = ftanh(acc[2][j]);
      float ov = fsig(acc[3][j]);
      c[j] = fv * c[j] + iv * gv;
      float hv = ov * ftanh(c[j]);
      const int rloc = lg * 4 + j;
      const int wbyte = (rloc * 256 + (wv * 16 + l15) * 2) ^ ((rloc & 7) << 4);
      union { _Float16 f; unsigned short u; } cv;
      cv.f = (_Float16)hv;
      *(_Float16*)(wb + wbyte) = cv.f;
      unsigned hb32 = cv.u;
      const void* hp = (const void*)(hex + ((size_t)s * 64 + rh * 16 + rloc) * 256
                                     + uh * 128 + wv * 16 + l15);
      asm volatile("global_store_short %0, %1, off sc0 sc1"
                   :: "v"(hp), "v"(hb32) : "memory");
    }
    __syncthreads();
    cur ^= 1;
  }
}

// ------ R10 sentinel scan (proven, 878us): 1 wave/block, 16u x 16r -----------
__global__ __launch_bounds__(64) void lstm_scan_sync(
    const half8_t* __restrict__ preF, const half8_t* __restrict__ wF,
    _Float16* __restrict__ hexF,
    const half8_t* __restrict__ preB, const half8_t* __restrict__ wB,
    _Float16* __restrict__ hexB, int nfwd) {
  const int isB = (blockIdx.x >= nfwd) ? 1 : 0;
  const half8_t* pre = isB ? preB : preF;
  const half8_t* wfrag = isB ? wB : wF;
  _Float16* hex = isB ? hexB : hexF;
  const int bid = blockIdx.x - (isB ? nfwd : 0);
  const int rg = bid >> 4, sl = bid & 15;
  const int w_ = sl >> 1, z_ = sl & 1;
  const int l = threadIdx.x, l15 = l & 15, lg = l >> 4;
  const int u0 = sl * 16;

  half8_t bfr[8][4];
#pragma unroll
  for (int ks = 0; ks < 8; ++ks)
#pragma unroll
    for (int g = 0; g < 4; ++g)
      bfr[ks][g] = wfrag[(size_t)((w_ * 8 + ks) * 8 + z_ * 4 + g) * 64 + l];

  float c[4] = {0.f, 0.f, 0.f, 0.f};
  half8_t pc0, pc1;
  {
    const int t0 = isB ? (Tt - 1) : 0;
    const half8_t* pp = pre + ((size_t)(t0 * 4 + rg) * 16 + sl) * 128 + l * 2;
    pc0 = pp[0]; pc1 = pp[1];
  }

  for (int s = 0; s < Tt; ++s) {
    f32x4 acc[4];
#pragma unroll
    for (int g = 0; g < 4; ++g)
#pragma unroll
      for (int j = 0; j < 4; ++j)
        acc[g][j] = (float)((g < 2 ? pc0 : pc1)[(g & 1) * 4 + j]);

    if (s + 1 < Tt) {
      const int tn = isB ? (Tt - 2 - s) : (s + 1);
      const half8_t* pp = pre + ((size_t)(tn * 4 + rg) * 16 + sl) * 128 + l * 2;
      pc0 = pp[0]; pc1 = pp[1];
    }

    if (s > 0) {
      const char* ab = (const char*)hex + (((size_t)(s - 1) * 64 + rg * 16) * 256) * 2;
      half8_t afr[8];
      while (true) {
#pragma unroll
        for (int ks = 0; ks < 8; ++ks) {
          const void* ap = (const void*)(ab + l15 * 512 + ks * 64 + lg * 16);
          asm volatile("global_load_dwordx4 %0, %1, off sc0 sc1"
                       : "=v"(afr[ks]) : "v"(ap) : "memory");
        }
        asm volatile("s_waitcnt vmcnt(0)" ::: "memory");
        union HU { half8_t h; u32x4 u; } cu;
        cu.h = afr[0];
        unsigned mm = pkmax16(pkmax16(cu.u[0], cu.u[1]), pkmax16(cu.u[2], cu.u[3]));
#pragma unroll
        for (int ks = 1; ks < 8; ++ks) {
          cu.h = afr[ks];
          mm = pkmax16(mm, pkmax16(pkmax16(cu.u[0], cu.u[1]), pkmax16(cu.u[2], cu.u[3])));
        }
        int bad = ((mm & 0xFFFFu) == 0x7C00u) || ((mm >> 16) == 0x7C00u);
        if (__all(!bad)) break;
      }
      __builtin_amdgcn_sched_barrier(0);

#pragma unroll
      for (int ks = 0; ks < 8; ++ks)
#pragma unroll
        for (int g = 0; g < 4; ++g)
          acc[g] = __builtin_amdgcn_mfma_f32_16x16x32_f16(afr[ks], bfr[ks][g], acc[g], 0, 0, 0);
    }

#pragma unroll
    for (int j = 0; j < 4; ++j) {
      float iv = fsig(acc[0][j]);
      float fv = fsig(acc[1][j]);
      float gv = ftanh(acc[2][j]);
      float ov = fsig(acc[3][j]);
      c[j] = fv * c[j] + iv * gv;
      float hv = ov * ftanh(c[j]);
      union { _Float16 f; unsigned short u; } cv;
      cv.f = (_Float16)hv;
      unsigned hb32 = cv.u;
      const void* hp = (const void*)(hex + ((size_t)s * 64 + rg * 16 + lg * 4 + j) * 256
                                     + u0 + l15);
      asm volatile("global_store_short %0, %1, off sc0 sc1"
                   :: "v"(hp), "v"(hb32) : "memory");
    }
  }
}

// ---------------- VQ: 4 vectors/block, 128 threads; writes qh fp16 ------------
#define VPB 4
__global__ __launch_bounds__(128) void vq_kernel(const _Float16* __restrict__ hexF,
                                                 const _Float16* __restrict__ hexB,
                                                 const float* __restrict__ cb,
                                                 _Float16* __restrict__ qh,
                                                 float* __restrict__ dmin) {
  const int tid = threadIdx.x;
  const int v0 = blockIdx.x * VPB;
  __shared__ __align__(16) float zs[VPB][Ee];
  __shared__ float dsh[NCODE];
  __shared__ int ish[NCODE];
  __shared__ int best[VPB];

#pragma unroll
  for (int v = 0; v < VPB; ++v) {
    const int vv = v0 + v;
    const int b = vv >> 9, t = vv & 511;
    const _Float16* hf = hexF + ((size_t)t * 64 + b) * 256;
    const _Float16* hb = hexB + ((size_t)(Tt - 1 - t) * 64 + b) * 256;
    zs[v][tid]       = (float)hf[tid];
    zs[v][tid + 128] = (float)hf[tid + 128];
    zs[v][tid + 256] = (float)hb[tid];
    zs[v][tid + 384] = (float)hb[tid + 128];
  }
  __syncthreads();

  float dv[VPB] = {0.0f, 0.0f, 0.0f, 0.0f};
  const float4* crow = (const float4*)(cb + (size_t)tid * Ee);
#pragma unroll 2
  for (int e4 = 0; e4 < Ee / 4; ++e4) {
    float4 cc = crow[e4];
#pragma unroll
    for (int v = 0; v < VPB; ++v) {
      float4 z = *(const float4*)&zs[v][e4 * 4];
      float t0 = z.x - cc.x, t1 = z.y - cc.y, t2 = z.z - cc.z, t3 = z.w - cc.w;
      dv[v] = fmaf(t0, t0, dv[v]);
      dv[v] = fmaf(t1, t1, dv[v]);
      dv[v] = fmaf(t2, t2, dv[v]);
      dv[v] = fmaf(t3, t3, dv[v]);
    }
  }

#pragma unroll
  for (int v = 0; v < VPB; ++v) {
    __syncthreads();
    dsh[tid] = dv[v];
    ish[tid] = tid;
    __syncthreads();
    for (int off = 64; off > 0; off >>= 1) {
      if (tid < off) {
        float dn = dsh[tid + off];
        int in_ = ish[tid + off];
        if (dn < dsh[tid] || (dn == dsh[tid] && in_ < ish[tid])) {
          dsh[tid] = dn;
          ish[tid] = in_;
        }
      }
      __syncthreads();
    }
    if (tid == 0) {
      best[v] = ish[0];
      dmin[v0 + v] = dsh[0];
    }
  }
  __syncthreads();

#pragma unroll
  for (int v = 0; v < VPB; ++v) {
    const float* cbest = cb + (size_t)best[v] * Ee;
    _Float16* qrow = qh + (size_t)(v0 + v) * Ee;
#pragma unroll
    for (int u = 0; u < 4; ++u) {
      int e = tid + u * 128;
      float z = zs[v][e];
      qrow[e] = (_Float16)(z + (cbest[e] - z));
    }
  }
}

// ---------------- vq loss reduce ----------------
__global__ __launch_bounds__(256) void vq_reduce(const float* __restrict__ dmin,
                                                 float* __restrict__ out) {
  __shared__ float sh[256];
  int tid = threadIdx.x;
  float s = 0.0f;
  for (int i = tid; i < Bb * Tt; i += 256) s += dmin[i];
  sh[tid] = s;
  __syncthreads();
  for (int off = 128; off > 0; off >>= 1) {
    if (tid < off) sh[tid] += sh[tid + off];
    __syncthreads();
  }
  if (tid == 0) out[Bb * NCLS] = sh[0] * (1.25f / ((float)(Bb * Tt) * (float)Ee));
}

// ---------------- decoder backward, single step at t=T-1 (h_prev=c_prev=0) ----
__global__ __launch_bounds__(256) void dec_bwd_last(const _Float16* __restrict__ qh,
                                                    const float* __restrict__ wpB,
                                                    const float* __restrict__ bias,
                                                    float* __restrict__ hb_last) {
  int b = blockIdx.x, tid = threadIdx.x;
  __shared__ __align__(16) float zsl[Ee];
  const _Float16* qrow = qh + ((size_t)b * Tt + (Tt - 1)) * Ee;
  zsl[tid] = (float)qrow[tid];
  zsl[tid + 256] = (float)qrow[tid + 256];
  __syncthreads();
  float a0 = bias[tid], a1 = bias[256 + tid], a2 = bias[512 + tid], a3 = bias[768 + tid];
  const float4* wp4 = (const float4*)wpB;
#pragma unroll 4
  for (int k = 0; k < Ee; ++k) {
    float zk = zsl[k];
    float4 w = wp4[((size_t)k << 8) + tid];
    a0 = fmaf(zk, w.x, a0); a1 = fmaf(zk, w.y, a1);
    a2 = fmaf(zk, w.z, a2); a3 = fmaf(zk, w.w, a3);
  }
  float i = sigf(a0), f = sigf(a1), g = tanhf(a2), o = sigf(a3);
  (void)f;
  float cc = i * g;
  hb_last[b * Hh + tid] = o * tanhf(cc);
}

// ---------------- classifier ----------------
__global__ __launch_bounds__(256) void classifier_k(const _Float16* __restrict__ hexD,
                                                    const float* __restrict__ hb_last,
                                                    const float* __restrict__ Wcls,
                                                    const float* __restrict__ bcls,
                                                    float* __restrict__ out) {
  int b = blockIdx.x, tid = threadIdx.x;
  __shared__ __align__(16) float dl[Ee];
  dl[tid] = (float)hexD[((size_t)(Tt - 1) * 64 + b) * 256 + tid];
  dl[tid + 256] = hb_last[b * Hh + tid];
  __syncthreads();
  if (tid < NCLS) {
    const float4* wr = (const float4*)(Wcls + (size_t)tid * Ee);
    float acc = bcls[tid];
#pragma unroll 4
    for (int e4 = 0; e4 < Ee / 4; ++e4) {
      float4 w = wr[e4];
      float4 z = *(const float4*)&dl[e4 * 4];
      acc = fmaf(w.x, z.x, acc);
      acc = fmaf(w.y, z.y, acc);
      acc = fmaf(w.z, z.z, acc);
      acc = fmaf(w.w, z.w, acc);
    }
    out[b * NCLS + tid] = acc;
  }
}

// ---------------- launch ----------------
extern "C" void kernel_launch(void* const* d_in, const int* in_sizes, int n_in,
                              void* d_out, int out_size, void* d_ws, size_t ws_size,
                              hipStream_t stream) {
  const float* x     = (const float*)d_in[0];
  const float* eWihF = (const float*)d_in[1];
  const float* eWhhF = (const float*)d_in[2];
  const float* ebF   = (const float*)d_in[3];
  const float* eWihB = (const float*)d_in[4];
  const float* eWhhB = (const float*)d_in[5];
  const float* ebB   = (const float*)d_in[6];
  const float* cb    = (const float*)d_in[7];
  const float* dWihF = (const float*)d_in[8];
  const float* dWhhF = (const float*)d_in[9];
  const float* dbF   = (const float*)d_in[10];
  const float* dWihB = (const float*)d_in[11];
  // d_in[12] = dec_Whh_b: unused (backward decoder state at t=T-1 starts from zero)
  const float* dbB   = (const float*)d_in[13];
  const float* Wcls  = (const float*)d_in[14];
  const float* bcls  = (const float*)d_in[15];
  float* out = (float*)d_out;
  float* w = (float*)d_ws;

  const size_t MR = (size_t)Bb * Tt;                 // 32768
  const size_t SZ_PRE_H = MR * G4 / 2;               // fp16 pre buffer, float units
  const size_t SZ_HEX  = (size_t)Tt * Bb * Hh / 2;   // fp16 exchange, float units
  const size_t SZ_XH   = MR * 256 / 2;               // xh fp16, float units
  const size_t SZ_WPK  = (size_t)512 * G4;           // dec_bwd fp32 pack
  const size_t SZ_WPH  = (size_t)G4 * Hh / 2;        // Whh frag pack, float units
  const size_t SZ_WIH  = (size_t)4 * 8 * 2 * 8 * 64 * 8 / 2;   // 131072 (enc, KS=8)
  const size_t SZ_WIHD = SZ_WIH * 2;                 // dec, KS=16

  size_t o = 0;
  __half* preFh = (__half*)(w + o); o += SZ_PRE_H;
  __half* preBh = (__half*)(w + o); o += SZ_PRE_H;
  _Float16* hexF = (_Float16*)(w + o); o += SZ_HEX;
  _Float16* hexB = (_Float16*)(w + o); o += SZ_HEX;
  _Float16* hexD = (_Float16*)(w + o); o += SZ_HEX;
  _Float16* xh = (_Float16*)(w + o); o += SZ_XH;
  float* wpkbd = w + o; o += SZ_WPK;
  _Float16* wphF = (_Float16*)(w + o); o += SZ_WPH;
  _Float16* wphB = (_Float16*)(w + o); o += SZ_WPH;
  _Float16* wphD = (_Float16*)(w + o); o += SZ_WPH;
  _Float16* wpihF = (_Float16*)(w + o); o += SZ_WIH;
  _Float16* wpihB = (_Float16*)(w + o); o += SZ_WIH;
  _Float16* wpihD = (_Float16*)(w + o); o += SZ_WIHD;
  float* dminp = w + o; o += MR;
  float* hbl   = w + o; o += (size_t)Bb * Hh;
  // aliases over dead regions
  _Float16* qh = (_Float16*)preFh;    // 32 MB fp16 over dead enc preF (post-scan)
  __half* dprf = preBh;               // dec fp16 pre over dead enc preB

  // 1. sentinel fill (hexF|hexB|hexD contiguous) + packs + x conversion
  hipLaunchKernelGGL(fill_inf4_k, dim3(2048), dim3(256), 0, stream,
                     (u32x4*)hexF, (long)(3 * SZ_HEX / 4));
  hipLaunchKernelGGL(conv_x_h, dim3((int)(MR * 256 / 256)), dim3(256), 0, stream, x, xh);
  hipLaunchKernelGGL(pack_w_k, dim3((G4 * 512) / 256), dim3(256), 0, stream, dWihB, wpkbd, 512);
  hipLaunchKernelGGL(pack_w_frag, dim3(1024), dim3(256), 0, stream, eWhhF, wphF);
  hipLaunchKernelGGL(pack_w_frag, dim3(1024), dim3(256), 0, stream, eWhhB, wphB);
  hipLaunchKernelGGL(pack_w_frag, dim3(1024), dim3(256), 0, stream, dWhhF, wphD);
  hipLaunchKernelGGL(pack_wih_frag, dim3(1024), dim3(256), 0, stream, eWihF, wpihF, INRAW, 3);
  hipLaunchKernelGGL(pack_wih_frag, dim3(1024), dim3(256), 0, stream, eWihB, wpihB, INRAW, 3);
  hipLaunchKernelGGL(pack_wih_frag, dim3(2048), dim3(256), 0, stream, dWihF, wpihD, Ee, 4);

  // 2. encoder input projections (MFMA)
  hipLaunchKernelGGL(gemm_mfma_pre, dim3(Tt, 4), dim3(256), 0, stream,
                     xh, wpihF, ebF, preFh, 256);
  hipLaunchKernelGGL(gemm_mfma_pre, dim3(Tt, 4), dim3(256), 0, stream,
                     xh, wpihB, ebB, preBh, 256);

  // 3. encoder scan: A/B — pairwise (16 blocks x 512 thr)
  hipLaunchKernelGGL(lstm_scan_pair, dim3(16), dim3(512), 0, stream,
                     (const half8_t*)preFh, (const half8_t*)wphF, hexF,
                     (const half8_t*)preBh, (const half8_t*)wphB, hexB, 8);

  // 4. VQ + loss (writes qh fp16 over dead preF)
  hipLaunchKernelGGL(vq_kernel, dim3((int)(MR / VPB)), dim3(128), 0, stream,
                     hexF, hexB, cb, qh, dminp);
  hipLaunchKernelGGL(vq_reduce, dim3(1), dim3(256), 0, stream, dminp, out);

  // 5. decoder fwd input projection (MFMA, K=512)
  hipLaunchKernelGGL(gemm_mfma_pre, dim3(Tt, 4), dim3(256), 0, stream,
                     qh, wpihD, dbF, dprf, 512);

  // 6. decoder bwd (only t=T-1 contributes)
  hipLaunchKernelGGL(dec_bwd_last, dim3(Bb), dim3(256), 0, stream, qh, wpkbd, dbB, hbl);

  // 7. decoder scan: A/B — R10-proven sentinel kernel (64 blocks x 64 thr)
  hipLaunchKernelGGL(lstm_scan_sync, dim3(64), dim3(64), 0, stream,
                     (const half8_t*)dprf, (const half8_t*)wphD, hexD,
                     (const half8_t*)dprf, (const half8_t*)wphD, hexD, 64);

  // 8. classifier
  hipLaunchKernelGGL(classifier_k, dim3(Bb), dim3(256), 0, stream,
                     hexD, hbl, Wcls, bcls, out);
}

// Round 14
// 2544.822 us; speedup vs baseline: 3.9654x; 1.1309x over previous
//
#include <hip/hip_runtime.h>
#include <hip/hip_fp16.h>
#include <cstddef>

#define Bb 64
#define Tt 512
#define INRAW 225
#define Hh 256
#define G4 1024
#define Ee 512
#define NCODE 128
#define NCLS 250

typedef _Float16 half8_t __attribute__((ext_vector_type(8)));
typedef float f32x4 __attribute__((ext_vector_type(4)));
typedef unsigned u32x4 __attribute__((ext_vector_type(4)));

__device__ __forceinline__ float sigf(float x) { return 1.0f / (1.0f + expf(-x)); }
__device__ __forceinline__ float fsig(float x) { return __builtin_amdgcn_rcpf(1.0f + __expf(-x)); }
__device__ __forceinline__ float ftanh(float x) {
  return 2.0f * __builtin_amdgcn_rcpf(1.0f + __expf(-2.0f * x)) - 1.0f;
}

// packed signed-int16 max (VOP3P); fp16 sentinel 0x7C00 is the int16 max among
// {finite |h|<=1 patterns} ∪ {0x7C00}, so a pk_max fold detects any sentinel.
__device__ __forceinline__ unsigned pkmax16(unsigned a, unsigned b) {
  unsigned r;
  asm("v_pk_max_i16 %0, %1, %2" : "=v"(r) : "v"(a), "v"(b));
  return r;
}

// ---- merged prep: [fill hex sentinels | conv x->fp16 | all weight packs] ----
// block ranges (256 thr each):
//   [0,24576)        fill 3*SZ_HEX halfs = 6,291,456 u32x4 stores (sc0 sc1)
//   [.., +32768)     conv_x_h (8,388,608 elems)
//   [.., +2048)      pack_w_k   dWihB -> wpkbd (K=512)
//   [.., +1024)x3    pack_w_frag eWhhF/eWhhB/dWhhF
//   [.., +1024)x2    pack_wih_frag eWihF/eWihB (Kraw=225, KS=8)
//   [.., +2048)      pack_wih_frag dWihF (Kraw=512, KS=16)
__global__ __launch_bounds__(256) void prep_all_k(
    u32x4* __restrict__ hexfill, const float* __restrict__ x, _Float16* __restrict__ xh,
    const float* __restrict__ dWihB, float* __restrict__ wpkbd,
    const float* __restrict__ eWhhF, _Float16* __restrict__ wphF,
    const float* __restrict__ eWhhB, _Float16* __restrict__ wphB,
    const float* __restrict__ dWhhF, _Float16* __restrict__ wphD,
    const float* __restrict__ eWihF, _Float16* __restrict__ wpihF,
    const float* __restrict__ eWihB, _Float16* __restrict__ wpihB,
    const float* __restrict__ dWihF, _Float16* __restrict__ wpihD) {
  int blk = blockIdx.x;
  const int tid = threadIdx.x;

  if (blk < 24576) {                       // sentinel fill
    long i = (long)blk * 256 + tid;        // < 6,291,456
    u32x4 v = {0x7C007C00u, 0x7C007C00u, 0x7C007C00u, 0x7C007C00u};
    asm volatile("global_store_dwordx4 %0, %1, off sc0 sc1"
                 :: "v"(hexfill + i), "v"(v) : "memory");
    return;
  }
  blk -= 24576;
  if (blk < 32768) {                       // conv x -> fp16 padded
    int idx = blk * 256 + tid;
    int row = idx >> 8, k = idx & 255;
    xh[idx] = (k < INRAW) ? (_Float16)x[(size_t)row * INRAW + k] : (_Float16)0.f;
    return;
  }
  blk -= 32768;
  if (blk < 2048) {                        // pack_w_k (dec_bwd fp32 pack, K=512)
    int idx = blk * 256 + tid;
    int jg = idx >> 9;                     // idx / 512
    int k = idx & 511;
    int j = jg >> 2, g = jg & 3;
    wpkbd[(((size_t)k << 8) + j) * 4 + g] = dWihB[(size_t)(g * 256 + j) * 512 + k];
    return;
  }
  blk -= 2048;
  if (blk < 3072) {                        // 3x pack_w_frag
    const float* W = (blk < 1024) ? eWhhF : (blk < 2048) ? eWhhB : dWhhF;
    _Float16* wp = (blk < 1024) ? wphF : (blk < 2048) ? wphB : wphD;
    int idx = (blk & 1023) * 256 + tid;
    int e = idx & 7, l = (idx >> 3) & 63, zg = (idx >> 9) & 7;
    int ks = (idx >> 12) & 7, wv = (idx >> 15) & 7;
    int z = zg >> 2, g = zg & 3;
    int u = wv * 32 + z * 16 + (l & 15);
    int k = ks * 32 + (l >> 4) * 8 + e;
    wp[idx] = (_Float16)W[(size_t)(g * 256 + u) * 256 + k];
    return;
  }
  blk -= 3072;
  if (blk < 2048) {                        // 2x pack_wih_frag enc (KS=8)
    const float* W = (blk < 1024) ? eWihF : eWihB;
    _Float16* wp = (blk < 1024) ? wpihF : wpihB;
    int idx = (blk & 1023) * 256 + tid;
    int e = idx & 7, l = (idx >> 3) & 63;
    int tail = idx >> 9;
    int ks = tail & 7; tail >>= 3;
    int z = tail & 1, w = (tail >> 1) & 7, g = tail >> 4;
    if (g >= 4) return;
    int k = ks * 32 + (l >> 4) * 8 + e;
    int u = w * 32 + z * 16 + (l & 15);
    wp[idx] = (k < INRAW) ? (_Float16)W[(size_t)(g * 256 + u) * INRAW + k] : (_Float16)0.f;
    return;
  }
  blk -= 2048;
  {                                        // pack_wih_frag dec (KS=16, 2048 blocks)
    int idx = blk * 256 + tid;
    int e = idx & 7, l = (idx >> 3) & 63;
    int tail = idx >> 9;
    int ks = tail & 15; tail >>= 4;
    int z = tail & 1, w = (tail >> 1) & 7, g = tail >> 4;
    if (g >= 4) return;
    int k = ks * 32 + (l >> 4) * 8 + e;
    int u = w * 32 + z * 16 + (l & 15);
    wpihD[idx] = (_Float16)dWihF[(size_t)(g * 256 + u) * 512 + k];
  }
}

// ---- MFMA input-projection GEMM: pre = A @ Wih^T + bias, fragment-layout out.
// grid (t=512, g=4, zsel); block 256 = 4 waves (batch-group). K = 256 or 512.
__global__ __launch_bounds__(256) void gemm_mfma_pre(const _Float16* __restrict__ Ah,
                                                     const _Float16* __restrict__ Bp0,
                                                     const float* __restrict__ bias0,
                                                     __half* __restrict__ C0,
                                                     const _Float16* __restrict__ Bp1,
                                                     const float* __restrict__ bias1,
                                                     __half* __restrict__ C1, int K) {
  const int t = blockIdx.x, g = blockIdx.y;
  const int zsel = blockIdx.z;
  const _Float16* Bp = zsel ? Bp1 : Bp0;
  const float* bias = zsel ? bias1 : bias0;
  __half* C = zsel ? C1 : C0;
  const int bg = threadIdx.x >> 6;
  const int l = threadIdx.x & 63, l15 = l & 15, lg = l >> 4;
  const int KS = K >> 5;

  f32x4 acc[16];
#pragma unroll
  for (int ct = 0; ct < 16; ++ct) acc[ct] = (f32x4){0.f, 0.f, 0.f, 0.f};

  const _Float16* arow = Ah + ((size_t)(bg * 16 + l15) * 512 + t) * K + lg * 8;

  for (int kh = 0; kh < KS; kh += 8) {
    half8_t af[8];
#pragma unroll
    for (int k2 = 0; k2 < 8; ++k2)
      af[k2] = *(const half8_t*)(arow + (kh + k2) * 32);
#pragma unroll
    for (int ct = 0; ct < 16; ++ct) {
      const int w = ct >> 1, z = ct & 1;
      const _Float16* bb = Bp + ((((size_t)(g * 8 + w) * 2 + z) * KS + kh) * 64 + l) * 8;
#pragma unroll
      for (int k2 = 0; k2 < 8; ++k2) {
        half8_t bf = *(const half8_t*)(bb + (size_t)k2 * 512);
        acc[ct] = __builtin_amdgcn_mfma_f32_16x16x32_f16(af[k2], bf, acc[ct], 0, 0, 0);
      }
    }
  }

#pragma unroll
  for (int ct = 0; ct < 16; ++ct) {
    const int w = ct >> 1, z = ct & 1;
    const int u = w * 32 + z * 16 + l15;
    const float bs = bias[g * 256 + u];
    union { unsigned short us[4]; uint2 u2; } pk;
#pragma unroll
    for (int j = 0; j < 4; ++j) {
      __half hv = __float2half(acc[ct][j] + bs);
      pk.us[j] = *(unsigned short*)&hv;
    }
    __half* dst = C + ((((size_t)t * 4 + bg) * 8 + w) * 2 + z) * 1024 + l * 16 + g * 4;
    *(uint2*)dst = pk.u2;
  }
}

// ------ multi-block LSTM scan (R10, verbatim): 1 wave/block, 16u x 16r.
// Sync = sentinel-poll on the data itself (no flags, no fences).
__global__ __launch_bounds__(64) void lstm_scan_sync(
    const half8_t* __restrict__ preF, const half8_t* __restrict__ wF,
    _Float16* __restrict__ hexF,
    const half8_t* __restrict__ preB, const half8_t* __restrict__ wB,
    _Float16* __restrict__ hexB, int nfwd) {
  const int isB = (blockIdx.x >= nfwd) ? 1 : 0;
  const half8_t* pre = isB ? preB : preF;
  const half8_t* wfrag = isB ? wB : wF;
  _Float16* hex = isB ? hexB : hexF;
  const int bid = blockIdx.x - (isB ? nfwd : 0);
  const int rg = bid >> 4, sl = bid & 15;
  const int w_ = sl >> 1, z_ = sl & 1;
  const int l = threadIdx.x, l15 = l & 15, lg = l >> 4;
  const int u0 = sl * 16;

  half8_t bfr[8][4];
#pragma unroll
  for (int ks = 0; ks < 8; ++ks)
#pragma unroll
    for (int g = 0; g < 4; ++g)
      bfr[ks][g] = wfrag[(size_t)((w_ * 8 + ks) * 8 + z_ * 4 + g) * 64 + l];

  float c[4] = {0.f, 0.f, 0.f, 0.f};
  half8_t pc0, pc1;
  {
    const int t0 = isB ? (Tt - 1) : 0;
    const half8_t* pp = pre + ((size_t)(t0 * 4 + rg) * 16 + sl) * 128 + l * 2;
    pc0 = pp[0]; pc1 = pp[1];
  }

  for (int s = 0; s < Tt; ++s) {
    f32x4 acc[4];
#pragma unroll
    for (int g = 0; g < 4; ++g)
#pragma unroll
      for (int j = 0; j < 4; ++j)
        acc[g][j] = (float)((g < 2 ? pc0 : pc1)[(g & 1) * 4 + j]);

    if (s + 1 < Tt) {
      const int tn = isB ? (Tt - 2 - s) : (s + 1);
      const half8_t* pp = pre + ((size_t)(tn * 4 + rg) * 16 + sl) * 128 + l * 2;
      pc0 = pp[0]; pc1 = pp[1];
    }

    if (s > 0) {
      const char* ab = (const char*)hex + (((size_t)(s - 1) * 64 + rg * 16) * 256) * 2;
      half8_t afr[8];
      while (true) {
#pragma unroll
        for (int ks = 0; ks < 8; ++ks) {
          const void* ap = (const void*)(ab + l15 * 512 + ks * 64 + lg * 16);
          asm volatile("global_load_dwordx4 %0, %1, off sc0 sc1"
                       : "=v"(afr[ks]) : "v"(ap) : "memory");
        }
        asm volatile("s_waitcnt vmcnt(0)" ::: "memory");
        union HU { half8_t h; u32x4 u; } cu;
        cu.h = afr[0];
        unsigned mm = pkmax16(pkmax16(cu.u[0], cu.u[1]), pkmax16(cu.u[2], cu.u[3]));
#pragma unroll
        for (int ks = 1; ks < 8; ++ks) {
          cu.h = afr[ks];
          mm = pkmax16(mm, pkmax16(pkmax16(cu.u[0], cu.u[1]), pkmax16(cu.u[2], cu.u[3])));
        }
        int bad = ((mm & 0xFFFFu) == 0x7C00u) || ((mm >> 16) == 0x7C00u);
        if (__all(!bad)) break;
      }
      __builtin_amdgcn_sched_barrier(0);

#pragma unroll
      for (int ks = 0; ks < 8; ++ks)
#pragma unroll
        for (int g = 0; g < 4; ++g)
          acc[g] = __builtin_amdgcn_mfma_f32_16x16x32_f16(afr[ks], bfr[ks][g], acc[g], 0, 0, 0);
    }

#pragma unroll
    for (int j = 0; j < 4; ++j) {
      float iv = fsig(acc[0][j]);
      float fv = fsig(acc[1][j]);
      float gv = ftanh(acc[2][j]);
      float ov = fsig(acc[3][j]);
      c[j] = fv * c[j] + iv * gv;
      float hv = ov * ftanh(c[j]);
      union { _Float16 f; unsigned short u; } cv;
      cv.f = (_Float16)hv;
      unsigned hb32 = cv.u;
      const void* hp = (const void*)(hex + ((size_t)s * 64 + rg * 16 + lg * 4 + j) * 256
                                     + u0 + l15);
      asm volatile("global_store_short %0, %1, off sc0 sc1"
                   :: "v"(hp), "v"(hb32) : "memory");
    }
  }
}

// ---------------- VQ: 4 vectors/block, 128 threads; writes qh fp16 ------------
#define VPB 4
__global__ __launch_bounds__(128) void vq_kernel(const _Float16* __restrict__ hexF,
                                                 const _Float16* __restrict__ hexB,
                                                 const float* __restrict__ cb,
                                                 _Float16* __restrict__ qh,
                                                 float* __restrict__ dmin) {
  const int tid = threadIdx.x;
  const int v0 = blockIdx.x * VPB;
  __shared__ __align__(16) float zs[VPB][Ee];
  __shared__ float dsh[NCODE];
  __shared__ int ish[NCODE];
  __shared__ int best[VPB];

#pragma unroll
  for (int v = 0; v < VPB; ++v) {
    const int vv = v0 + v;
    const int b = vv >> 9, t = vv & 511;
    const _Float16* hf = hexF + ((size_t)t * 64 + b) * 256;
    const _Float16* hb = hexB + ((size_t)(Tt - 1 - t) * 64 + b) * 256;
    zs[v][tid]       = (float)hf[tid];
    zs[v][tid + 128] = (float)hf[tid + 128];
    zs[v][tid + 256] = (float)hb[tid];
    zs[v][tid + 384] = (float)hb[tid + 128];
  }
  __syncthreads();

  float dv[VPB] = {0.0f, 0.0f, 0.0f, 0.0f};
  const float4* crow = (const float4*)(cb + (size_t)tid * Ee);
#pragma unroll 2
  for (int e4 = 0; e4 < Ee / 4; ++e4) {
    float4 cc = crow[e4];
#pragma unroll
    for (int v = 0; v < VPB; ++v) {
      float4 z = *(const float4*)&zs[v][e4 * 4];
      float t0 = z.x - cc.x, t1 = z.y - cc.y, t2 = z.z - cc.z, t3 = z.w - cc.w;
      dv[v] = fmaf(t0, t0, dv[v]);
      dv[v] = fmaf(t1, t1, dv[v]);
      dv[v] = fmaf(t2, t2, dv[v]);
      dv[v] = fmaf(t3, t3, dv[v]);
    }
  }

#pragma unroll
  for (int v = 0; v < VPB; ++v) {
    __syncthreads();
    dsh[tid] = dv[v];
    ish[tid] = tid;
    __syncthreads();
    for (int off = 64; off > 0; off >>= 1) {
      if (tid < off) {
        float dn = dsh[tid + off];
        int in_ = ish[tid + off];
        if (dn < dsh[tid] || (dn == dsh[tid] && in_ < ish[tid])) {
          dsh[tid] = dn;
          ish[tid] = in_;
        }
      }
      __syncthreads();
    }
    if (tid == 0) {
      best[v] = ish[0];
      dmin[v0 + v] = dsh[0];
    }
  }
  __syncthreads();

#pragma unroll
  for (int v = 0; v < VPB; ++v) {
    const float* cbest = cb + (size_t)best[v] * Ee;
    _Float16* qrow = qh + (size_t)(v0 + v) * Ee;
#pragma unroll
    for (int u = 0; u < 4; ++u) {
      int e = tid + u * 128;
      float z = zs[v][e];
      qrow[e] = (_Float16)(z + (cbest[e] - z));
    }
  }
}

// ---------------- vq loss reduce (1024 threads) ----------------
__global__ __launch_bounds__(1024) void vq_reduce(const float* __restrict__ dmin,
                                                  float* __restrict__ out) {
  __shared__ float sh[1024];
  int tid = threadIdx.x;
  float s = 0.0f;
  for (int i = tid; i < Bb * Tt; i += 1024) s += dmin[i];
  sh[tid] = s;
  __syncthreads();
  for (int off = 512; off > 0; off >>= 1) {
    if (tid < off) sh[tid] += sh[tid + off];
    __syncthreads();
  }
  if (tid == 0) out[Bb * NCLS] = sh[0] * (1.25f / ((float)(Bb * Tt) * (float)Ee));
}

// ---------------- decoder backward, single step at t=T-1 (h_prev=c_prev=0) ----
__global__ __launch_bounds__(256) void dec_bwd_last(const _Float16* __restrict__ qh,
                                                    const float* __restrict__ wpB,
                                                    const float* __restrict__ bias,
                                                    float* __restrict__ hb_last) {
  int b = blockIdx.x, tid = threadIdx.x;
  __shared__ __align__(16) float zsl[Ee];
  const _Float16* qrow = qh + ((size_t)b * Tt + (Tt - 1)) * Ee;
  zsl[tid] = (float)qrow[tid];
  zsl[tid + 256] = (float)qrow[tid + 256];
  __syncthreads();
  float a0 = bias[tid], a1 = bias[256 + tid], a2 = bias[512 + tid], a3 = bias[768 + tid];
  const float4* wp4 = (const float4*)wpB;
#pragma unroll 4
  for (int k = 0; k < Ee; ++k) {
    float zk = zsl[k];
    float4 w = wp4[((size_t)k << 8) + tid];
    a0 = fmaf(zk, w.x, a0); a1 = fmaf(zk, w.y, a1);
    a2 = fmaf(zk, w.z, a2); a3 = fmaf(zk, w.w, a3);
  }
  float i = sigf(a0), f = sigf(a1), g = tanhf(a2), o = sigf(a3);
  (void)f;
  float cc = i * g;
  hb_last[b * Hh + tid] = o * tanhf(cc);
}

// ---------------- classifier ----------------
__global__ __launch_bounds__(256) void classifier_k(const _Float16* __restrict__ hexD,
                                                    const float* __restrict__ hb_last,
                                                    const float* __restrict__ Wcls,
                                                    const float* __restrict__ bcls,
                                                    float* __restrict__ out) {
  int b = blockIdx.x, tid = threadIdx.x;
  __shared__ __align__(16) float dl[Ee];
  dl[tid] = (float)hexD[((size_t)(Tt - 1) * 64 + b) * 256 + tid];
  dl[tid + 256] = hb_last[b * Hh + tid];
  __syncthreads();
  if (tid < NCLS) {
    const float4* wr = (const float4*)(Wcls + (size_t)tid * Ee);
    float acc = bcls[tid];
#pragma unroll 4
    for (int e4 = 0; e4 < Ee / 4; ++e4) {
      float4 w = wr[e4];
      float4 z = *(const float4*)&dl[e4 * 4];
      acc = fmaf(w.x, z.x, acc);
      acc = fmaf(w.y, z.y, acc);
      acc = fmaf(w.z, z.z, acc);
      acc = fmaf(w.w, z.w, acc);
    }
    out[b * NCLS + tid] = acc;
  }
}

// ---------------- launch ----------------
extern "C" void kernel_launch(void* const* d_in, const int* in_sizes, int n_in,
                              void* d_out, int out_size, void* d_ws, size_t ws_size,
                              hipStream_t stream) {
  const float* x     = (const float*)d_in[0];
  const float* eWihF = (const float*)d_in[1];
  const float* eWhhF = (const float*)d_in[2];
  const float* ebF   = (const float*)d_in[3];
  const float* eWihB = (const float*)d_in[4];
  const float* eWhhB = (const float*)d_in[5];
  const float* ebB   = (const float*)d_in[6];
  const float* cb    = (const float*)d_in[7];
  const float* dWihF = (const float*)d_in[8];
  const float* dWhhF = (const float*)d_in[9];
  const float* dbF   = (const float*)d_in[10];
  const float* dWihB = (const float*)d_in[11];
  // d_in[12] = dec_Whh_b: unused (backward decoder state at t=T-1 starts from zero)
  const float* dbB   = (const float*)d_in[13];
  const float* Wcls  = (const float*)d_in[14];
  const float* bcls  = (const float*)d_in[15];
  float* out = (float*)d_out;
  float* w = (float*)d_ws;

  const size_t MR = (size_t)Bb * Tt;                 // 32768
  const size_t SZ_PRE_H = MR * G4 / 2;               // fp16 pre buffer, float units
  const size_t SZ_HEX  = (size_t)Tt * Bb * Hh / 2;   // fp16 exchange, float units
  const size_t SZ_XH   = MR * 256 / 2;               // xh fp16, float units
  const size_t SZ_WPK  = (size_t)512 * G4;           // dec_bwd fp32 pack
  const size_t SZ_WPH  = (size_t)G4 * Hh / 2;        // Whh frag pack, float units
  const size_t SZ_WIH  = (size_t)4 * 8 * 2 * 8 * 64 * 8 / 2;   // 131072 (enc, KS=8)
  const size_t SZ_WIHD = SZ_WIH * 2;                 // dec, KS=16

  size_t o = 0;
  __half* preFh = (__half*)(w + o); o += SZ_PRE_H;
  __half* preBh = (__half*)(w + o); o += SZ_PRE_H;
  _Float16* hexF = (_Float16*)(w + o); o += SZ_HEX;
  _Float16* hexB = (_Float16*)(w + o); o += SZ_HEX;
  _Float16* hexD = (_Float16*)(w + o); o += SZ_HEX;
  _Float16* xh = (_Float16*)(w + o); o += SZ_XH;
  float* wpkbd = w + o; o += SZ_WPK;
  _Float16* wphF = (_Float16*)(w + o); o += SZ_WPH;
  _Float16* wphB = (_Float16*)(w + o); o += SZ_WPH;
  _Float16* wphD = (_Float16*)(w + o); o += SZ_WPH;
  _Float16* wpihF = (_Float16*)(w + o); o += SZ_WIH;
  _Float16* wpihB = (_Float16*)(w + o); o += SZ_WIH;
  _Float16* wpihD = (_Float16*)(w + o); o += SZ_WIHD;
  float* dminp = w + o; o += MR;
  float* hbl   = w + o; o += (size_t)Bb * Hh;
  // aliases over dead regions
  _Float16* qh = (_Float16*)preFh;    // 32 MB fp16 over dead enc preF (post-scan)
  __half* dprf = preBh;               // dec fp16 pre over dead enc preB

  // 1. merged prep: sentinel fill + x conv + all weight packs (one dispatch)
  hipLaunchKernelGGL(prep_all_k, dim3(66560), dim3(256), 0, stream,
                     (u32x4*)hexF, x, xh,
                     dWihB, wpkbd,
                     eWhhF, wphF, eWhhB, wphB, dWhhF, wphD,
                     eWihF, wpihF, eWihB, wpihB, dWihF, wpihD);

  // 2. encoder input projections (MFMA, both directions in one dispatch)
  hipLaunchKernelGGL(gemm_mfma_pre, dim3(Tt, 4, 2), dim3(256), 0, stream,
                     xh, wpihF, ebF, preFh, wpihB, ebB, preBh, 256);

  // 3. encoder scan: 128 one-wave blocks (64 fwd + 64 bwd)
  hipLaunchKernelGGL(lstm_scan_sync, dim3(128), dim3(64), 0, stream,
                     (const half8_t*)preFh, (const half8_t*)wphF, hexF,
                     (const half8_t*)preBh, (const half8_t*)wphB, hexB, 64);

  // 4. VQ + loss (writes qh fp16 over dead preF)
  hipLaunchKernelGGL(vq_kernel, dim3((int)(MR / VPB)), dim3(128), 0, stream,
                     hexF, hexB, cb, qh, dminp);
  hipLaunchKernelGGL(vq_reduce, dim3(1), dim3(1024), 0, stream, dminp, out);

  // 5. decoder fwd input projection (MFMA, K=512)
  hipLaunchKernelGGL(gemm_mfma_pre, dim3(Tt, 4, 1), dim3(256), 0, stream,
                     qh, wpihD, dbF, dprf, wpihD, dbF, dprf, 512);

  // 6. decoder bwd (only t=T-1 contributes)
  hipLaunchKernelGGL(dec_bwd_last, dim3(Bb), dim3(256), 0, stream, qh, wpkbd, dbB, hbl);

  // 7. decoder fwd scan: 64 one-wave blocks
  hipLaunchKernelGGL(lstm_scan_sync, dim3(64), dim3(64), 0, stream,
                     (const half8_t*)dprf, (const half8_t*)wphD, hexD,
                     (const half8_t*)dprf, (const half8_t*)wphD, hexD, 64);

  // 8. classifier
  hipLaunchKernelGGL(classifier_k, dim3(Bb), dim3(256), 0, stream,
                     hexD, hbl, Wcls, bcls, out);
}